// Round 1
// baseline (3119.556 us; speedup 1.0000x reference)
//
#include <hip/hip_runtime.h>
#include <hip/hip_bf16.h>

#define EMB 64

// ---- degree count via int atomics over row ----
__global__ void deg_kernel(const int* __restrict__ row, int* __restrict__ degi, int E) {
    int e = blockIdx.x * blockDim.x + threadIdx.x;
    if (e < E) atomicAdd(&degi[row[e]], 1);
}

// ---- dinv = rsqrt(deg + 1) ----
__global__ void dinv_kernel(const int* __restrict__ degi, float* __restrict__ dinv, int N) {
    int i = blockIdx.x * blockDim.x + threadIdx.x;
    if (i < N) dinv[i] = rsqrtf((float)degi[i] + 1.0f);
}

// ---- x0 = concat(user_emb, item_emb); out = x0 ----
__global__ void init_kernel(const float* __restrict__ u, const float* __restrict__ it,
                            float* __restrict__ x, float* __restrict__ out,
                            long nu_elems, long total) {
    long j = (long)blockIdx.x * blockDim.x + threadIdx.x;
    if (j < total) {
        float v = (j < nu_elems) ? u[j] : it[j - nu_elems];
        x[j] = v;
        out[j] = v;
    }
}

// ---- xn = dinv[i]^2 * xc  (self-loop term, also zero-inits xn) ----
__global__ void self_kernel(const float* __restrict__ xc, float* __restrict__ xn,
                            const float* __restrict__ dinv, long total) {
    long j = (long)blockIdx.x * blockDim.x + threadIdx.x;
    if (j < total) {
        int i = (int)(j >> 6);
        float dv = dinv[i];
        xn[j] = dv * dv * xc[j];
    }
}

// ---- edge scatter: xn[row, d] += dinv[row]*dinv[col] * xc[col, d] ----
__global__ void scatter_kernel(const int* __restrict__ row, const int* __restrict__ col,
                               const float* __restrict__ dinv,
                               const float* __restrict__ xc, float* __restrict__ xn,
                               long E) {
    long t = (long)blockIdx.x * blockDim.x + threadIdx.x;
    long e = t >> 6;
    int d = (int)(t & 63);
    if (e < E) {
        int r = row[e];
        int c = col[e];
        float w = dinv[r] * dinv[c];
        atomicAdd(&xn[(long)r * EMB + d], w * xc[(long)c * EMB + d]);
    }
}

// ---- out += xn ----
__global__ void acc_kernel(float* __restrict__ out, const float* __restrict__ xn, long total) {
    long j = (long)blockIdx.x * blockDim.x + threadIdx.x;
    if (j < total) out[j] += xn[j];
}

extern "C" void kernel_launch(void* const* d_in, const int* in_sizes, int n_in,
                              void* d_out, int out_size, void* d_ws, size_t ws_size,
                              hipStream_t stream) {
    const int*   edge_index = (const int*)d_in[0];   // [2, E]
    const float* user_emb   = (const float*)d_in[1]; // [NU, 64]
    const float* item_emb   = (const float*)d_in[2]; // [NI, 64]
    float* out = (float*)d_out;

    const long E  = in_sizes[0] / 2;
    const int  NU = in_sizes[1] / EMB;
    const int  NI = in_sizes[2] / EMB;
    const int  N  = NU + NI;
    const long total = (long)N * EMB;

    const int* row = edge_index;
    const int* col = edge_index + E;

    // workspace layout (floats): dinv[N] | degi[N] | x0[N*64] | x1[N*64]
    float* dinv = (float*)d_ws;
    int*   degi = (int*)(dinv + N);
    float* x0   = (float*)(degi + N);
    float* x1   = x0 + total;

    hipMemsetAsync(degi, 0, (size_t)N * sizeof(int), stream);

    {
        int threads = 256;
        long blocks = (E + threads - 1) / threads;
        deg_kernel<<<(int)blocks, threads, 0, stream>>>(row, degi, (int)E);
    }
    {
        int threads = 256;
        int blocks = (N + threads - 1) / threads;
        dinv_kernel<<<blocks, threads, 0, stream>>>(degi, dinv, N);
    }
    {
        int threads = 256;
        long blocks = (total + threads - 1) / threads;
        init_kernel<<<(int)blocks, threads, 0, stream>>>(user_emb, item_emb, x0, out,
                                                         (long)NU * EMB, total);
    }

    float* xc = x0;
    float* xn = x1;
    for (int layer = 0; layer < 3; ++layer) {
        {
            int threads = 256;
            long blocks = (total + threads - 1) / threads;
            self_kernel<<<(int)blocks, threads, 0, stream>>>(xc, xn, dinv, total);
        }
        {
            int threads = 256;
            long work = E * EMB;
            long blocks = (work + threads - 1) / threads;
            scatter_kernel<<<(int)blocks, threads, 0, stream>>>(row, col, dinv, xc, xn, E);
        }
        {
            int threads = 256;
            long blocks = (total + threads - 1) / threads;
            acc_kernel<<<(int)blocks, threads, 0, stream>>>(out, xn, total);
        }
        float* tmp = xc; xc = xn; xn = tmp;
    }
}

// Round 2
// 1353.617 us; speedup vs baseline: 2.3046x; 2.3046x over previous
//
#include <hip/hip_runtime.h>
#include <hip/hip_bf16.h>

#define EMB 64

// ---- degree count via int atomics over row ----
__global__ void deg_kernel(const int* __restrict__ row, int* __restrict__ degi, int E) {
    int e = blockIdx.x * blockDim.x + threadIdx.x;
    if (e < E) atomicAdd(&degi[row[e]], 1);
}

// ---- dinv = rsqrt(deg + 1) ----
__global__ void dinv_kernel(const int* __restrict__ degi, float* __restrict__ dinv, int N) {
    int i = blockIdx.x * blockDim.x + threadIdx.x;
    if (i < N) dinv[i] = rsqrtf((float)degi[i] + 1.0f);
}

// ---- exclusive scan, step 1: per-block (1024 elems) scan + block partial ----
__global__ void scan1_kernel(const int* __restrict__ deg, int* __restrict__ excl,
                             int* __restrict__ partials, int N) {
    __shared__ int sh[256];
    int b = blockIdx.x, t = threadIdx.x;
    int base = b * 1024 + t * 4;
    int d0 = (base + 0 < N) ? deg[base + 0] : 0;
    int d1 = (base + 1 < N) ? deg[base + 1] : 0;
    int d2 = (base + 2 < N) ? deg[base + 2] : 0;
    int d3 = (base + 3 < N) ? deg[base + 3] : 0;
    int tsum = d0 + d1 + d2 + d3;
    sh[t] = tsum;
    __syncthreads();
    for (int off = 1; off < 256; off <<= 1) {
        int v = (t >= off) ? sh[t - off] : 0;
        __syncthreads();
        sh[t] += v;
        __syncthreads();
    }
    int excl_t = sh[t] - tsum;
    if (base + 0 < N) excl[base + 0] = excl_t;
    if (base + 1 < N) excl[base + 1] = excl_t + d0;
    if (base + 2 < N) excl[base + 2] = excl_t + d0 + d1;
    if (base + 3 < N) excl[base + 3] = excl_t + d0 + d1 + d2;
    if (t == 255) partials[b] = sh[t];
}

// ---- scan step 2: single block exclusive-scans the partials (nb <= 512) ----
__global__ void scan2_kernel(int* __restrict__ partials, int nb) {
    __shared__ int sh[512];
    int t = threadIdx.x;
    int v = (t < nb) ? partials[t] : 0;
    sh[t] = v;
    __syncthreads();
    for (int off = 1; off < 512; off <<= 1) {
        int u = (t >= off) ? sh[t - off] : 0;
        __syncthreads();
        sh[t] += u;
        __syncthreads();
    }
    if (t < nb) partials[t] = sh[t] - v;  // exclusive
}

// ---- scan step 3: row_ptr[i] = excl[i] + partials[i/1024]; also cursor copy ----
__global__ void scan3_kernel(const int* __restrict__ excl, const int* __restrict__ partials,
                             int* __restrict__ row_ptr, int* __restrict__ cursor, int N, int E) {
    int i = blockIdx.x * blockDim.x + threadIdx.x;
    if (i < N) {
        int v = excl[i] + partials[i >> 10];
        row_ptr[i] = v;
        cursor[i]  = v;
    }
    if (i == N) row_ptr[N] = E;
}

// ---- CSR fill: sorted col ids + precomputed edge weights ----
__global__ void fill_kernel(const int* __restrict__ row, const int* __restrict__ col,
                            const float* __restrict__ dinv,
                            int* __restrict__ cursor,
                            int* __restrict__ cols, float* __restrict__ wvals, int E) {
    int e = blockIdx.x * blockDim.x + threadIdx.x;
    if (e < E) {
        int r = row[e];
        int c = col[e];
        int pos = atomicAdd(&cursor[r], 1);
        cols[pos]  = c;
        wvals[pos] = dinv[r] * dinv[c];
    }
}

// ---- x0 = concat(user_emb, item_emb); out = x0 ----
__global__ void init_kernel(const float* __restrict__ u, const float* __restrict__ it,
                            float* __restrict__ x, float* __restrict__ out,
                            long nu_elems, long total) {
    long j = (long)blockIdx.x * blockDim.x + threadIdx.x;
    if (j < total) {
        float v = (j < nu_elems) ? u[j] : it[j - nu_elems];
        x[j] = v;
        out[j] = v;
    }
}

// ---- fused gather SpMM: one wave per node, lane = dim ----
// xn[i,:] = dinv[i]^2 * xc[i,:] + sum_k w_k * xc[cols_k,:] ; out[i,:] += xn[i,:]
__global__ void spmm_kernel(const int* __restrict__ row_ptr, const int* __restrict__ cols,
                            const float* __restrict__ wvals, const float* __restrict__ dinv,
                            const float* __restrict__ xc, float* __restrict__ xn,
                            float* __restrict__ out, int N) {
    int wave = (int)((blockIdx.x * (long)blockDim.x + threadIdx.x) >> 6);
    int lane = threadIdx.x & 63;
    if (wave >= N) return;
    int i = wave;
    float di = dinv[i];
    long base = (long)i * EMB + lane;
    float acc = di * di * xc[base];
    int s = row_ptr[i], e = row_ptr[i + 1];
    int k = s;
    for (; k + 3 < e; k += 4) {
        int c0 = cols[k], c1 = cols[k + 1], c2 = cols[k + 2], c3 = cols[k + 3];
        float w0 = wvals[k], w1 = wvals[k + 1], w2 = wvals[k + 2], w3 = wvals[k + 3];
        float v0 = xc[(long)c0 * EMB + lane];
        float v1 = xc[(long)c1 * EMB + lane];
        float v2 = xc[(long)c2 * EMB + lane];
        float v3 = xc[(long)c3 * EMB + lane];
        acc += w0 * v0 + w1 * v1 + w2 * v2 + w3 * v3;
    }
    for (; k < e; ++k) {
        int c = cols[k];
        acc += wvals[k] * xc[(long)c * EMB + lane];
    }
    if (xn) xn[base] = acc;
    out[base] += acc;
}

extern "C" void kernel_launch(void* const* d_in, const int* in_sizes, int n_in,
                              void* d_out, int out_size, void* d_ws, size_t ws_size,
                              hipStream_t stream) {
    const int*   edge_index = (const int*)d_in[0];   // [2, E]
    const float* user_emb   = (const float*)d_in[1]; // [NU, 64]
    const float* item_emb   = (const float*)d_in[2]; // [NI, 64]
    float* out = (float*)d_out;

    const int  E  = in_sizes[0] / 2;
    const int  NU = in_sizes[1] / EMB;
    const int  NI = in_sizes[2] / EMB;
    const int  N  = NU + NI;
    const long total = (long)N * EMB;

    const int* row = edge_index;
    const int* col = edge_index + E;

    // workspace layout:
    // dinv[N] f | degi[N] i | excl[N] i | partials[512] i | row_ptr[N+1] i |
    // cursor[N] i | cols[E] i | wvals[E] f | x0[N*64] f | x1[N*64] f
    float* dinv     = (float*)d_ws;
    int*   degi     = (int*)(dinv + N);
    int*   excl     = degi + N;
    int*   partials = excl + N;
    int*   row_ptr  = partials + 512;
    int*   cursor   = row_ptr + (N + 1);
    int*   cols     = cursor + N;
    float* wvals    = (float*)(cols + E);
    float* x0       = wvals + E;
    // align x0 up to 16B
    x0 = (float*)(((uintptr_t)x0 + 15) & ~(uintptr_t)15);
    float* x1 = x0 + total;

    hipMemsetAsync(degi, 0, (size_t)N * sizeof(int), stream);

    deg_kernel<<<(E + 255) / 256, 256, 0, stream>>>(row, degi, E);

    int nb = (N + 1023) / 1024;  // <= 512 for N <= 524288
    scan1_kernel<<<nb, 256, 0, stream>>>(degi, excl, partials, N);
    scan2_kernel<<<1, 512, 0, stream>>>(partials, nb);
    scan3_kernel<<<(N + 1 + 255) / 256, 256, 0, stream>>>(excl, partials, row_ptr, cursor, N, E);

    dinv_kernel<<<(N + 255) / 256, 256, 0, stream>>>(degi, dinv, N);

    fill_kernel<<<(E + 255) / 256, 256, 0, stream>>>(row, col, dinv, cursor, cols, wvals, E);

    init_kernel<<<(int)((total + 255) / 256), 256, 0, stream>>>(user_emb, item_emb, x0, out,
                                                                (long)NU * EMB, total);

    float* xc = x0;
    float* xn = x1;
    for (int layer = 0; layer < 3; ++layer) {
        float* xn_arg = (layer == 2) ? nullptr : xn;
        int blocks = (N + 3) / 4;  // 4 waves (nodes) per 256-thread block
        spmm_kernel<<<blocks, 256, 0, stream>>>(row_ptr, cols, wvals, dinv, xc, xn_arg, out, N);
        float* tmp = xc; xc = xn; xn = tmp;
    }
}

// Round 3
// 1106.250 us; speedup vs baseline: 2.8199x; 1.2236x over previous
//
#include <hip/hip_runtime.h>
#include <hip/hip_bf16.h>

#define EMB 64

// ---- user row_ptr via binary search over sorted first half of row ----
__global__ void urp_kernel(const int* __restrict__ row, int* __restrict__ urp, int NU, int Eh) {
    int r = blockIdx.x * blockDim.x + threadIdx.x;
    if (r > NU) return;
    if (r == NU) { urp[NU] = Eh; return; }
    int lo = 0, hi = Eh;
    while (lo < hi) {
        int mid = (lo + hi) >> 1;
        if (row[mid] < r) lo = mid + 1; else hi = mid;
    }
    urp[r] = lo;
}

// ---- item degree histogram over first-half cols (item ids) ----
__global__ void ideg_kernel(const int* __restrict__ colh, int* __restrict__ degit, int Eh, int NU) {
    int e = blockIdx.x * blockDim.x + threadIdx.x;
    if (e < Eh) atomicAdd(&degit[colh[e] - NU], 1);
}

// ---- dinv = rsqrt(deg + 1) for all N nodes ----
__global__ void dinv_kernel(const int* __restrict__ urp, const int* __restrict__ degit,
                            float* __restrict__ dinv, int NU, int N) {
    int i = blockIdx.x * blockDim.x + threadIdx.x;
    if (i >= N) return;
    int d = (i < NU) ? (urp[i + 1] - urp[i]) : degit[i - NU];
    dinv[i] = rsqrtf((float)d + 1.0f);
}

// ---- exclusive scan over item degrees: per-block scan + partials ----
__global__ void scan1_kernel(const int* __restrict__ deg, int* __restrict__ excl,
                             int* __restrict__ partials, int N) {
    __shared__ int sh[256];
    int b = blockIdx.x, t = threadIdx.x;
    int base = b * 1024 + t * 4;
    int d0 = (base + 0 < N) ? deg[base + 0] : 0;
    int d1 = (base + 1 < N) ? deg[base + 1] : 0;
    int d2 = (base + 2 < N) ? deg[base + 2] : 0;
    int d3 = (base + 3 < N) ? deg[base + 3] : 0;
    int tsum = d0 + d1 + d2 + d3;
    sh[t] = tsum;
    __syncthreads();
    for (int off = 1; off < 256; off <<= 1) {
        int v = (t >= off) ? sh[t - off] : 0;
        __syncthreads();
        sh[t] += v;
        __syncthreads();
    }
    int excl_t = sh[t] - tsum;
    if (base + 0 < N) excl[base + 0] = excl_t;
    if (base + 1 < N) excl[base + 1] = excl_t + d0;
    if (base + 2 < N) excl[base + 2] = excl_t + d0 + d1;
    if (base + 3 < N) excl[base + 3] = excl_t + d0 + d1 + d2;
    if (t == 255) partials[b] = sh[t];
}

__global__ void scan2_kernel(int* __restrict__ partials, int nb) {
    __shared__ int sh[512];
    int t = threadIdx.x;
    int v = (t < nb) ? partials[t] : 0;
    sh[t] = v;
    __syncthreads();
    for (int off = 1; off < 512; off <<= 1) {
        int u = (t >= off) ? sh[t - off] : 0;
        __syncthreads();
        sh[t] += u;
        __syncthreads();
    }
    if (t < nb) partials[t] = sh[t] - v;  // exclusive
}

__global__ void scan3_kernel(const int* __restrict__ excl, const int* __restrict__ partials,
                             int* __restrict__ irp, int* __restrict__ cursor, int N, int E) {
    int i = blockIdx.x * blockDim.x + threadIdx.x;
    if (i < N) {
        int v = excl[i] + partials[i >> 10];
        irp[i] = v;
        cursor[i] = v;
    }
    if (i == N) irp[N] = E;
}

// ---- item CSR fill: scatter user ids into per-item segments ----
__global__ void ifill_kernel(const int* __restrict__ rowh, const int* __restrict__ colh,
                             int* __restrict__ cursor, int* __restrict__ icols, int Eh, int NU) {
    int e = blockIdx.x * blockDim.x + threadIdx.x;
    if (e < Eh) {
        int u = rowh[e];
        int itl = colh[e] - NU;
        int pos = atomicAdd(&cursor[itl], 1);
        icols[pos] = u;
    }
}

// ---- x0 = concat(user_emb, item_emb) ----
__global__ void init_kernel(const float* __restrict__ u, const float* __restrict__ it,
                            float* __restrict__ x, long nu_elems, long total) {
    long j = (long)blockIdx.x * blockDim.x + threadIdx.x;
    if (j < total) x[j] = (j < nu_elems) ? u[j] : it[j - nu_elems];
}

// ---- fused gather SpMM: one wave per node, 4 edges x 16 lanes x float4 ----
// acc = dinv[i]^2*xc[i,:] + sum_k dinv[i]*dinv[c_k]*xc[c_k,:]
// first: out = xc + acc ; else out += acc. xn (if non-null) = acc.
__global__ void spmm_kernel(const int* __restrict__ urp, const int* __restrict__ irp,
                            const int* __restrict__ colg, const int* __restrict__ icols,
                            const float* __restrict__ dinv,
                            const float* __restrict__ xc, float* __restrict__ xn,
                            float* __restrict__ out, int NU, int N, int first) {
    int wave = (int)(((long)blockIdx.x * blockDim.x + threadIdx.x) >> 6);
    if (wave >= N) return;
    int lane = threadIdx.x & 63;
    int sub = lane >> 4;     // edge slot 0..3
    int q   = lane & 15;     // float4 index 0..15
    int i = wave;
    const int* list;
    int s, e;
    if (i < NU) { s = urp[i]; e = urp[i + 1]; list = colg; }
    else        { int j = i - NU; s = irp[j]; e = irp[j + 1]; list = icols; }
    float di = dinv[i];
    const float4* __restrict__ xc4 = (const float4*)xc;

    float4 acc = make_float4(0.f, 0.f, 0.f, 0.f);
    for (int k0 = s; k0 < e; k0 += 4) {
        int k = k0 + sub;
        bool valid = (k < e);
        int c = valid ? list[k] : 0;
        float w = valid ? di * dinv[c] : 0.0f;
        float4 v = xc4[(long)c * 16 + q];
        acc.x += w * v.x; acc.y += w * v.y; acc.z += w * v.z; acc.w += w * v.w;
    }
    // reduce the 4 edge-slot partials (lanes l, l+16, l+32, l+48)
    for (int off = 16; off < 64; off <<= 1) {
        acc.x += __shfl_xor(acc.x, off);
        acc.y += __shfl_xor(acc.y, off);
        acc.z += __shfl_xor(acc.z, off);
        acc.w += __shfl_xor(acc.w, off);
    }
    if (lane < 16) {
        long p = (long)i * 16 + q;
        float4 sv = xc4[p];
        float sw = di * di;
        acc.x += sw * sv.x; acc.y += sw * sv.y; acc.z += sw * sv.z; acc.w += sw * sv.w;
        if (xn) ((float4*)xn)[p] = acc;
        float4 o;
        if (first) {
            o.x = sv.x + acc.x; o.y = sv.y + acc.y; o.z = sv.z + acc.z; o.w = sv.w + acc.w;
        } else {
            float4 oo = ((const float4*)out)[p];
            o.x = oo.x + acc.x; o.y = oo.y + acc.y; o.z = oo.z + acc.z; o.w = oo.w + acc.w;
        }
        ((float4*)out)[p] = o;
    }
}

extern "C" void kernel_launch(void* const* d_in, const int* in_sizes, int n_in,
                              void* d_out, int out_size, void* d_ws, size_t ws_size,
                              hipStream_t stream) {
    const int*   edge_index = (const int*)d_in[0];   // [2, E]
    const float* user_emb   = (const float*)d_in[1]; // [NU, 64]
    const float* item_emb   = (const float*)d_in[2]; // [NI, 64]
    float* out = (float*)d_out;

    const int  E  = in_sizes[0] / 2;
    const int  Eh = E / 2;             // first half: user rows (sorted), cols = items
    const int  NU = in_sizes[1] / EMB;
    const int  NI = in_sizes[2] / EMB;
    const int  N  = NU + NI;
    const long total = (long)N * EMB;

    const int* row = edge_index;       // [E]
    const int* col = edge_index + E;   // [E]
    const int* rowh = row;             // first Eh entries: sorted user ids
    const int* colh = col;             // first Eh entries: item ids (random)

    // workspace layout (ints unless noted):
    // urp[NU+1] | degit[NI] | excl[NI] | partials[512] | irp[NI+1] | cursor[NI] |
    // icols[Eh] | dinv[N] f | x0[N*64] f | x1[N*64] f
    int*   urp      = (int*)d_ws;
    int*   degit    = urp + (NU + 1);
    int*   excl     = degit + NI;
    int*   partials = excl + NI;
    int*   irp      = partials + 512;
    int*   cursor   = irp + (NI + 1);
    int*   icols    = cursor + NI;
    float* dinv     = (float*)(icols + Eh);
    float* x0       = dinv + N;
    x0 = (float*)(((uintptr_t)x0 + 15) & ~(uintptr_t)15);
    float* x1 = x0 + total;

    hipMemsetAsync(degit, 0, (size_t)NI * sizeof(int), stream);

    urp_kernel<<<(NU + 256) / 256, 256, 0, stream>>>(row, urp, NU, Eh);
    ideg_kernel<<<(Eh + 255) / 256, 256, 0, stream>>>(colh, degit, Eh, NU);
    dinv_kernel<<<(N + 255) / 256, 256, 0, stream>>>(urp, degit, dinv, NU, N);

    int nb = (NI + 1023) / 1024;  // <= 512
    scan1_kernel<<<nb, 256, 0, stream>>>(degit, excl, partials, NI);
    scan2_kernel<<<1, 512, 0, stream>>>(partials, nb);
    scan3_kernel<<<(NI + 1 + 255) / 256, 256, 0, stream>>>(excl, partials, irp, cursor, NI, Eh);

    ifill_kernel<<<(Eh + 255) / 256, 256, 0, stream>>>(rowh, colh, cursor, icols, Eh, NU);

    init_kernel<<<(int)((total + 255) / 256), 256, 0, stream>>>(user_emb, item_emb, x0,
                                                                (long)NU * EMB, total);

    float* xc = x0;
    float* xn = x1;
    for (int layer = 0; layer < 3; ++layer) {
        float* xn_arg = (layer == 2) ? nullptr : xn;
        int blocks = (N + 3) / 4;  // 4 waves (nodes) per 256-thread block
        spmm_kernel<<<blocks, 256, 0, stream>>>(urp, irp, col, icols, dinv, xc, xn_arg, out,
                                                NU, N, layer == 0 ? 1 : 0);
        float* tmp = xc; xc = xn; xn = tmp;
    }
}

// Round 4
// 997.651 us; speedup vs baseline: 3.1269x; 1.1089x over previous
//
#include <hip/hip_runtime.h>
#include <hip/hip_bf16.h>

#define EMB 64

__device__ __forceinline__ float bf2f(unsigned short h) {
    return __uint_as_float(((unsigned)h) << 16);
}
__device__ __forceinline__ unsigned short f2bf(float f) {
    unsigned u = __float_as_uint(f);
    unsigned r = (u + 0x7fffu + ((u >> 16) & 1u)) >> 16;  // RNE
    return (unsigned short)r;
}

// ---- user row_ptr via binary search over sorted first half of row ----
__global__ void urp_kernel(const int* __restrict__ row, int* __restrict__ urp, int NU, int Eh) {
    int r = blockIdx.x * blockDim.x + threadIdx.x;
    if (r > NU) return;
    if (r == NU) { urp[NU] = Eh; return; }
    int lo = 0, hi = Eh;
    while (lo < hi) {
        int mid = (lo + hi) >> 1;
        if (row[mid] < r) lo = mid + 1; else hi = mid;
    }
    urp[r] = lo;
}

// ---- item degree histogram over first-half cols (item ids) ----
__global__ void ideg_kernel(const int* __restrict__ colh, int* __restrict__ degit, int Eh, int NU) {
    int e = blockIdx.x * blockDim.x + threadIdx.x;
    if (e < Eh) atomicAdd(&degit[colh[e] - NU], 1);
}

// ---- dinv = rsqrt(deg + 1) for all N nodes ----
__global__ void dinv_kernel(const int* __restrict__ urp, const int* __restrict__ degit,
                            float* __restrict__ dinv, int NU, int N) {
    int i = blockIdx.x * blockDim.x + threadIdx.x;
    if (i >= N) return;
    int d = (i < NU) ? (urp[i + 1] - urp[i]) : degit[i - NU];
    dinv[i] = rsqrtf((float)d + 1.0f);
}

// ---- exclusive scan over item degrees ----
__global__ void scan1_kernel(const int* __restrict__ deg, int* __restrict__ excl,
                             int* __restrict__ partials, int N) {
    __shared__ int sh[256];
    int b = blockIdx.x, t = threadIdx.x;
    int base = b * 1024 + t * 4;
    int d0 = (base + 0 < N) ? deg[base + 0] : 0;
    int d1 = (base + 1 < N) ? deg[base + 1] : 0;
    int d2 = (base + 2 < N) ? deg[base + 2] : 0;
    int d3 = (base + 3 < N) ? deg[base + 3] : 0;
    int tsum = d0 + d1 + d2 + d3;
    sh[t] = tsum;
    __syncthreads();
    for (int off = 1; off < 256; off <<= 1) {
        int v = (t >= off) ? sh[t - off] : 0;
        __syncthreads();
        sh[t] += v;
        __syncthreads();
    }
    int excl_t = sh[t] - tsum;
    if (base + 0 < N) excl[base + 0] = excl_t;
    if (base + 1 < N) excl[base + 1] = excl_t + d0;
    if (base + 2 < N) excl[base + 2] = excl_t + d0 + d1;
    if (base + 3 < N) excl[base + 3] = excl_t + d0 + d1 + d2;
    if (t == 255) partials[b] = sh[t];
}

__global__ void scan2_kernel(int* __restrict__ partials, int nb) {
    __shared__ int sh[512];
    int t = threadIdx.x;
    int v = (t < nb) ? partials[t] : 0;
    sh[t] = v;
    __syncthreads();
    for (int off = 1; off < 512; off <<= 1) {
        int u = (t >= off) ? sh[t - off] : 0;
        __syncthreads();
        sh[t] += u;
        __syncthreads();
    }
    if (t < nb) partials[t] = sh[t] - v;  // exclusive
}

__global__ void scan3_kernel(const int* __restrict__ excl, const int* __restrict__ partials,
                             int* __restrict__ irp, int* __restrict__ cursor, int N, int E) {
    int i = blockIdx.x * blockDim.x + threadIdx.x;
    if (i < N) {
        int v = excl[i] + partials[i >> 10];
        irp[i] = v;
        cursor[i] = v;
    }
    if (i == N) irp[N] = E;
}

// ---- item CSR fill: scatter user ids into per-item segments ----
__global__ void ifill_kernel(const int* __restrict__ rowh, const int* __restrict__ colh,
                             int* __restrict__ cursor, int* __restrict__ icols, int Eh, int NU) {
    int e = blockIdx.x * blockDim.x + threadIdx.x;
    if (e < Eh) {
        int u = rowh[e];
        int itl = colh[e] - NU;
        int pos = atomicAdd(&cursor[itl], 1);
        icols[pos] = u;
    }
}

// ---- x0 = bf16(concat(user_emb, item_emb)) ----
__global__ void init_kernel(const float* __restrict__ u, const float* __restrict__ it,
                            unsigned short* __restrict__ x, long nu_elems, long total) {
    long j = (long)blockIdx.x * blockDim.x + threadIdx.x;
    if (j < total) {
        float v = (j < nu_elems) ? u[j] : it[j - nu_elems];
        x[j] = f2bf(v);
    }
}

// ---- fused gather SpMM over bf16 x: one wave per node, 8 edges/iter, float4-equiv lanes ----
// acc = dinv[i]^2*xc[i,:] + sum_k dinv[i]*dinv[c_k]*xc[c_k,:]
// if xn: xn = bf16(acc); else (final layer): out = f32(x0)+f32(x1)+f32(xc)+acc
__global__ void spmm_kernel(const int* __restrict__ urp, const int* __restrict__ irp,
                            const int* __restrict__ colg, const int* __restrict__ icols,
                            const float* __restrict__ dinv,
                            const unsigned short* __restrict__ xc,
                            unsigned short* __restrict__ xn,
                            const unsigned short* __restrict__ x0b,
                            const unsigned short* __restrict__ x1b,
                            float* __restrict__ out, int NU, int N) {
    int wave = (int)(((long)blockIdx.x * blockDim.x + threadIdx.x) >> 6);
    if (wave >= N) return;
    int lane = threadIdx.x & 63;
    int sub = lane >> 4;     // edge slot 0..3
    int q   = lane & 15;     // ushort4 index 0..15 (4 elems each)
    int i = wave;
    const int* list;
    int s, e;
    if (i < NU) { s = urp[i]; e = urp[i + 1]; list = colg; }
    else        { int j = i - NU; s = irp[j]; e = irp[j + 1]; list = icols; }
    float di = dinv[i];
    const ushort4* __restrict__ xc4 = (const ushort4*)xc;

    float ax = 0.f, ay = 0.f, az = 0.f, aw = 0.f;
    for (int k0 = s; k0 < e; k0 += 8) {
        int ka = k0 + sub;
        int kb = k0 + 4 + sub;
        bool va = ka < e, vb = kb < e;
        int ca = va ? list[ka] : 0;
        int cb = vb ? list[kb] : 0;
        float wa = va ? di * dinv[ca] : 0.0f;
        float wb = vb ? di * dinv[cb] : 0.0f;
        ushort4 ua = xc4[(long)ca * 16 + q];
        ushort4 ub = xc4[(long)cb * 16 + q];
        ax += wa * bf2f(ua.x) + wb * bf2f(ub.x);
        ay += wa * bf2f(ua.y) + wb * bf2f(ub.y);
        az += wa * bf2f(ua.z) + wb * bf2f(ub.z);
        aw += wa * bf2f(ua.w) + wb * bf2f(ub.w);
    }
    // reduce the 4 edge-slot partials (lanes l, l+16, l+32, l+48)
    for (int off = 16; off < 64; off <<= 1) {
        ax += __shfl_xor(ax, off);
        ay += __shfl_xor(ay, off);
        az += __shfl_xor(az, off);
        aw += __shfl_xor(aw, off);
    }
    if (lane < 16) {
        long p = (long)i * 16 + q;
        ushort4 sv = xc4[p];
        float sw = di * di;
        ax += sw * bf2f(sv.x);
        ay += sw * bf2f(sv.y);
        az += sw * bf2f(sv.z);
        aw += sw * bf2f(sv.w);
        if (xn) {
            ushort4 o;
            o.x = f2bf(ax); o.y = f2bf(ay); o.z = f2bf(az); o.w = f2bf(aw);
            ((ushort4*)xn)[p] = o;
        } else {
            ushort4 a0 = ((const ushort4*)x0b)[p];
            ushort4 a1 = ((const ushort4*)x1b)[p];
            float4 o;
            o.x = bf2f(a0.x) + bf2f(a1.x) + bf2f(sv.x) + ax;
            o.y = bf2f(a0.y) + bf2f(a1.y) + bf2f(sv.y) + ay;
            o.z = bf2f(a0.z) + bf2f(a1.z) + bf2f(sv.z) + az;
            o.w = bf2f(a0.w) + bf2f(a1.w) + bf2f(sv.w) + aw;
            ((float4*)out)[p] = o;
        }
    }
}

extern "C" void kernel_launch(void* const* d_in, const int* in_sizes, int n_in,
                              void* d_out, int out_size, void* d_ws, size_t ws_size,
                              hipStream_t stream) {
    const int*   edge_index = (const int*)d_in[0];   // [2, E]
    const float* user_emb   = (const float*)d_in[1]; // [NU, 64]
    const float* item_emb   = (const float*)d_in[2]; // [NI, 64]
    float* out = (float*)d_out;

    const int  E  = in_sizes[0] / 2;
    const int  Eh = E / 2;             // first half: user rows (sorted), cols = items
    const int  NU = in_sizes[1] / EMB;
    const int  NI = in_sizes[2] / EMB;
    const int  N  = NU + NI;
    const long total = (long)N * EMB;

    const int* row = edge_index;       // [E]
    const int* col = edge_index + E;   // [E]
    const int* rowh = row;             // first Eh: sorted user ids
    const int* colh = col;             // first Eh: item ids (random)

    // workspace layout:
    // urp[NU+1] | degit[NI] | excl[NI] | partials[512] | irp[NI+1] | cursor[NI] |
    // icols[Eh] | dinv[N] f | x0[total] bf16 | x1[total] bf16 | x2[total] bf16
    int*   urp      = (int*)d_ws;
    int*   degit    = urp + (NU + 1);
    int*   excl     = degit + NI;
    int*   partials = excl + NI;
    int*   irp      = partials + 512;
    int*   cursor   = irp + (NI + 1);
    int*   icols    = cursor + NI;
    float* dinv     = (float*)(icols + Eh);
    unsigned short* x0 = (unsigned short*)(dinv + N);
    x0 = (unsigned short*)(((uintptr_t)x0 + 15) & ~(uintptr_t)15);
    unsigned short* x1 = x0 + total;
    unsigned short* x2 = x1 + total;

    hipMemsetAsync(degit, 0, (size_t)NI * sizeof(int), stream);

    urp_kernel<<<(NU + 256) / 256, 256, 0, stream>>>(row, urp, NU, Eh);
    ideg_kernel<<<(Eh + 255) / 256, 256, 0, stream>>>(colh, degit, Eh, NU);
    dinv_kernel<<<(N + 255) / 256, 256, 0, stream>>>(urp, degit, dinv, NU, N);

    int nb = (NI + 1023) / 1024;  // <= 512
    scan1_kernel<<<nb, 256, 0, stream>>>(degit, excl, partials, NI);
    scan2_kernel<<<1, 512, 0, stream>>>(partials, nb);
    scan3_kernel<<<(NI + 1 + 255) / 256, 256, 0, stream>>>(excl, partials, irp, cursor, NI, Eh);

    ifill_kernel<<<(Eh + 255) / 256, 256, 0, stream>>>(rowh, colh, cursor, icols, Eh, NU);

    init_kernel<<<(int)((total + 255) / 256), 256, 0, stream>>>(user_emb, item_emb, x0,
                                                                (long)NU * EMB, total);

    int blocks = (N + 3) / 4;  // 4 waves (nodes) per 256-thread block
    // L0: x1 = A(x0)
    spmm_kernel<<<blocks, 256, 0, stream>>>(urp, irp, col, icols, dinv, x0, x1,
                                            nullptr, nullptr, nullptr, NU, N);
    // L1: x2 = A(x1)
    spmm_kernel<<<blocks, 256, 0, stream>>>(urp, irp, col, icols, dinv, x1, x2,
                                            nullptr, nullptr, nullptr, NU, N);
    // L2 (fused final): out = x0 + x1 + x2 + A(x2)
    spmm_kernel<<<blocks, 256, 0, stream>>>(urp, irp, col, icols, dinv, x2, nullptr,
                                            x0, x1, out, NU, N);
}

// Round 5
// 984.060 us; speedup vs baseline: 3.1701x; 1.0138x over previous
//
#include <hip/hip_runtime.h>
#include <hip/hip_bf16.h>

#define EMB 64

__device__ __forceinline__ float bf2f(unsigned short h) {
    return __uint_as_float(((unsigned)h) << 16);
}
__device__ __forceinline__ unsigned short f2bf(float f) {
    unsigned u = __float_as_uint(f);
    unsigned r = (u + 0x7fffu + ((u >> 16) & 1u)) >> 16;  // RNE
    return (unsigned short)r;
}

// ---- user row_ptr via binary search over sorted first half of row ----
__global__ void urp_kernel(const int* __restrict__ row, int* __restrict__ urp, int NU, int Eh) {
    int r = blockIdx.x * blockDim.x + threadIdx.x;
    if (r > NU) return;
    if (r == NU) { urp[NU] = Eh; return; }
    int lo = 0, hi = Eh;
    while (lo < hi) {
        int mid = (lo + hi) >> 1;
        if (row[mid] < r) lo = mid + 1; else hi = mid;
    }
    urp[r] = lo;
}

// ---- item degree histogram over first-half cols (item ids) ----
__global__ void ideg_kernel(const int* __restrict__ colh, int* __restrict__ degit, int Eh, int NU) {
    int e = blockIdx.x * blockDim.x + threadIdx.x;
    if (e < Eh) atomicAdd(&degit[colh[e] - NU], 1);
}

// ---- dinv = rsqrt(deg + 1) for all N nodes ----
__global__ void dinv_kernel(const int* __restrict__ urp, const int* __restrict__ degit,
                            float* __restrict__ dinv, int NU, int N) {
    int i = blockIdx.x * blockDim.x + threadIdx.x;
    if (i >= N) return;
    int d = (i < NU) ? (urp[i + 1] - urp[i]) : degit[i - NU];
    dinv[i] = rsqrtf((float)d + 1.0f);
}

// ---- exclusive scan over item degrees ----
__global__ void scan1_kernel(const int* __restrict__ deg, int* __restrict__ excl,
                             int* __restrict__ partials, int N) {
    __shared__ int sh[256];
    int b = blockIdx.x, t = threadIdx.x;
    int base = b * 1024 + t * 4;
    int d0 = (base + 0 < N) ? deg[base + 0] : 0;
    int d1 = (base + 1 < N) ? deg[base + 1] : 0;
    int d2 = (base + 2 < N) ? deg[base + 2] : 0;
    int d3 = (base + 3 < N) ? deg[base + 3] : 0;
    int tsum = d0 + d1 + d2 + d3;
    sh[t] = tsum;
    __syncthreads();
    for (int off = 1; off < 256; off <<= 1) {
        int v = (t >= off) ? sh[t - off] : 0;
        __syncthreads();
        sh[t] += v;
        __syncthreads();
    }
    int excl_t = sh[t] - tsum;
    if (base + 0 < N) excl[base + 0] = excl_t;
    if (base + 1 < N) excl[base + 1] = excl_t + d0;
    if (base + 2 < N) excl[base + 2] = excl_t + d0 + d1;
    if (base + 3 < N) excl[base + 3] = excl_t + d0 + d1 + d2;
    if (t == 255) partials[b] = sh[t];
}

__global__ void scan2_kernel(int* __restrict__ partials, int nb) {
    __shared__ int sh[512];
    int t = threadIdx.x;
    int v = (t < nb) ? partials[t] : 0;
    sh[t] = v;
    __syncthreads();
    for (int off = 1; off < 512; off <<= 1) {
        int u = (t >= off) ? sh[t - off] : 0;
        __syncthreads();
        sh[t] += u;
        __syncthreads();
    }
    if (t < nb) partials[t] = sh[t] - v;  // exclusive
}

__global__ void scan3_kernel(const int* __restrict__ excl, const int* __restrict__ partials,
                             int* __restrict__ irp, int* __restrict__ cursor, int N, int E) {
    int i = blockIdx.x * blockDim.x + threadIdx.x;
    if (i < N) {
        int v = excl[i] + partials[i >> 10];
        irp[i] = v;
        cursor[i] = v;
    }
    if (i == N) irp[N] = E;
}

// ---- item CSR fill: scatter user ids into per-item segments ----
__global__ void ifill_kernel(const int* __restrict__ rowh, const int* __restrict__ colh,
                             int* __restrict__ cursor, int* __restrict__ icols, int Eh, int NU) {
    int e = blockIdx.x * blockDim.x + threadIdx.x;
    if (e < Eh) {
        int u = rowh[e];
        int itl = colh[e] - NU;
        int pos = atomicAdd(&cursor[itl], 1);
        icols[pos] = u;
    }
}

// ---- x0 = bf16(concat(user_emb, item_emb)) ----
__global__ void init_kernel(const float* __restrict__ u, const float* __restrict__ it,
                            unsigned short* __restrict__ x, long nu_elems, long total) {
    long j = (long)blockIdx.x * blockDim.x + threadIdx.x;
    if (j < total) {
        float v = (j < nu_elems) ? u[j] : it[j - nu_elems];
        x[j] = f2bf(v);
    }
}

// ---- fused gather SpMM over bf16 x: one wave per node, 16 edges/iter ----
// acc = dinv[i]^2*xc[i,:] + sum_k dinv[i]*dinv[c_k]*xc[c_k,:]
// if xn: xn = bf16(acc); else (final layer): out = f32(x0)+f32(x1)+f32(xc)+acc
__global__ void spmm_kernel(const int* __restrict__ urp, const int* __restrict__ irp,
                            const int* __restrict__ colg, const int* __restrict__ icols,
                            const float* __restrict__ dinv,
                            const unsigned short* __restrict__ xc,
                            unsigned short* __restrict__ xn,
                            const unsigned short* __restrict__ x0b,
                            const unsigned short* __restrict__ x1b,
                            float* __restrict__ out, int NU, int N) {
    int wave = (int)(((long)blockIdx.x * blockDim.x + threadIdx.x) >> 6);
    if (wave >= N) return;
    int lane = threadIdx.x & 63;
    int sub = lane >> 4;     // edge slot group 0..3
    int q   = lane & 15;     // ushort4 index 0..15
    int i = wave;
    const int* list;
    int s, e;
    if (i < NU) { s = urp[i]; e = urp[i + 1]; list = colg; }
    else        { int j = i - NU; s = irp[j]; e = irp[j + 1]; list = icols; }
    float di = dinv[i];
    const ushort4* __restrict__ xc4 = (const ushort4*)xc;

    // hoist independent self-row load (one 128B row, broadcast across lane groups)
    long p = (long)i * 16 + q;
    ushort4 sv = xc4[p];

    float ax = 0.f, ay = 0.f, az = 0.f, aw = 0.f;
    for (int k0 = s; k0 < e; k0 += 16) {
        int kbase = k0 + sub * 4;  // this slot's 4 consecutive edges
        int   c[4];
        float w[4];
#pragma unroll
        for (int j = 0; j < 4; ++j) {
            int k = kbase + j;
            bool v = (k < e);
            c[j] = v ? list[k] : 0;
            w[j] = v ? di * dinv[c[j]] : 0.0f;
        }
#pragma unroll
        for (int j = 0; j < 4; ++j) {
            ushort4 u = xc4[(long)c[j] * 16 + q];
            ax += w[j] * bf2f(u.x);
            ay += w[j] * bf2f(u.y);
            az += w[j] * bf2f(u.z);
            aw += w[j] * bf2f(u.w);
        }
    }
    // reduce the 4 slot partials (lanes l, l+16, l+32, l+48)
    for (int off = 16; off < 64; off <<= 1) {
        ax += __shfl_xor(ax, off);
        ay += __shfl_xor(ay, off);
        az += __shfl_xor(az, off);
        aw += __shfl_xor(aw, off);
    }
    if (lane < 16) {
        float sw = di * di;
        ax += sw * bf2f(sv.x);
        ay += sw * bf2f(sv.y);
        az += sw * bf2f(sv.z);
        aw += sw * bf2f(sv.w);
        if (xn) {
            ushort4 o;
            o.x = f2bf(ax); o.y = f2bf(ay); o.z = f2bf(az); o.w = f2bf(aw);
            ((ushort4*)xn)[p] = o;
        } else {
            ushort4 a0 = ((const ushort4*)x0b)[p];
            ushort4 a1 = ((const ushort4*)x1b)[p];
            float4 o;
            o.x = bf2f(a0.x) + bf2f(a1.x) + bf2f(sv.x) + ax;
            o.y = bf2f(a0.y) + bf2f(a1.y) + bf2f(sv.y) + ay;
            o.z = bf2f(a0.z) + bf2f(a1.z) + bf2f(sv.z) + az;
            o.w = bf2f(a0.w) + bf2f(a1.w) + bf2f(sv.w) + aw;
            ((float4*)out)[p] = o;
        }
    }
}

extern "C" void kernel_launch(void* const* d_in, const int* in_sizes, int n_in,
                              void* d_out, int out_size, void* d_ws, size_t ws_size,
                              hipStream_t stream) {
    const int*   edge_index = (const int*)d_in[0];   // [2, E]
    const float* user_emb   = (const float*)d_in[1]; // [NU, 64]
    const float* item_emb   = (const float*)d_in[2]; // [NI, 64]
    float* out = (float*)d_out;

    const int  E  = in_sizes[0] / 2;
    const int  Eh = E / 2;             // first half: user rows (sorted), cols = items
    const int  NU = in_sizes[1] / EMB;
    const int  NI = in_sizes[2] / EMB;
    const int  N  = NU + NI;
    const long total = (long)N * EMB;

    const int* row = edge_index;       // [E]
    const int* col = edge_index + E;   // [E]
    const int* rowh = row;             // first Eh: sorted user ids
    const int* colh = col;             // first Eh: item ids (random)

    // workspace layout:
    // urp[NU+1] | degit[NI] | excl[NI] | partials[512] | irp[NI+1] | cursor[NI] |
    // icols[Eh] | dinv[N] f | x0[total] bf16 | x1[total] bf16 | x2[total] bf16
    int*   urp      = (int*)d_ws;
    int*   degit    = urp + (NU + 1);
    int*   excl     = degit + NI;
    int*   partials = excl + NI;
    int*   irp      = partials + 512;
    int*   cursor   = irp + (NI + 1);
    int*   icols    = cursor + NI;
    float* dinv     = (float*)(icols + Eh);
    unsigned short* x0 = (unsigned short*)(dinv + N);
    x0 = (unsigned short*)(((uintptr_t)x0 + 15) & ~(uintptr_t)15);
    unsigned short* x1 = x0 + total;
    unsigned short* x2 = x1 + total;

    hipMemsetAsync(degit, 0, (size_t)NI * sizeof(int), stream);

    urp_kernel<<<(NU + 256) / 256, 256, 0, stream>>>(row, urp, NU, Eh);
    ideg_kernel<<<(Eh + 255) / 256, 256, 0, stream>>>(colh, degit, Eh, NU);
    dinv_kernel<<<(N + 255) / 256, 256, 0, stream>>>(urp, degit, dinv, NU, N);

    int nb = (NI + 1023) / 1024;  // <= 512
    scan1_kernel<<<nb, 256, 0, stream>>>(degit, excl, partials, NI);
    scan2_kernel<<<1, 512, 0, stream>>>(partials, nb);
    scan3_kernel<<<(NI + 1 + 255) / 256, 256, 0, stream>>>(excl, partials, irp, cursor, NI, Eh);

    ifill_kernel<<<(Eh + 255) / 256, 256, 0, stream>>>(rowh, colh, cursor, icols, Eh, NU);

    init_kernel<<<(int)((total + 255) / 256), 256, 0, stream>>>(user_emb, item_emb, x0,
                                                                (long)NU * EMB, total);

    int blocks = (N + 3) / 4;  // 4 waves (nodes) per 256-thread block
    // L0: x1 = A(x0)
    spmm_kernel<<<blocks, 256, 0, stream>>>(urp, irp, col, icols, dinv, x0, x1,
                                            nullptr, nullptr, nullptr, NU, N);
    // L1: x2 = A(x1)
    spmm_kernel<<<blocks, 256, 0, stream>>>(urp, irp, col, icols, dinv, x1, x2,
                                            nullptr, nullptr, nullptr, NU, N);
    // L2 (fused final): out = x0 + x1 + x2 + A(x2)
    spmm_kernel<<<blocks, 256, 0, stream>>>(urp, irp, col, icols, dinv, x2, nullptr,
                                            x0, x1, out, NU, N);
}